// Round 4
// baseline (7096.944 us; speedup 1.0000x reference)
//
#include <hip/hip_runtime.h>
#include <math.h>

#define NN   192
#define DIN_ 67
#define DM_  512
#define NHD  8
#define DH_  64
#define DFF_ 2048
#define GHC  32
#define NCLS 1000
#define BFULL 256
#define SPLITK 6

// ------------------------------------------------------------------
// PE table: pe[n, 2i] = sin(n * exp(2i * -ln(1e4)/512)), pe[n,2i+1]=cos
// computed in double to match numpy float64 -> float32 reference
// ------------------------------------------------------------------
__global__ void pe_kernel(float* __restrict__ pe) {
  int n = blockIdx.x;      // 0..191
  int i = threadIdx.x;     // 0..255
  double div = exp((double)(2 * i) * (-log(10000.0) / (double)DM_));
  double a = (double)n * div;
  pe[n * DM_ + 2 * i]     = (float)sin(a);
  pe[n * DM_ + 2 * i + 1] = (float)cos(a);
}

// ------------------------------------------------------------------
// Generic fp32 tiled GEMM (64x64 tile):  C = act(A[M,K] @ W[N,K]^T + ...)
// FLAGS: 1 = relu, 2 = add res[M,N], 4 = add pe[(m%192)*512 + n]
// ------------------------------------------------------------------
#define BM 64
#define BN 64
#define BK 16
#define LDT 68

template <int FLAGS>
__global__ __launch_bounds__(256) void gemm_nt(
    const float* __restrict__ A, const float* __restrict__ W,
    const float* __restrict__ bias, const float* __restrict__ res,
    const float* __restrict__ pe, float* __restrict__ C,
    int M, int K, int N)
{
  __shared__ __align__(16) float As[BK][LDT];
  __shared__ __align__(16) float Ws[BK][LDT];
  const int tid  = threadIdx.x;
  const int m0   = blockIdx.x * BM;
  const int n0   = blockIdx.y * BN;
  const int ty   = tid >> 4;
  const int tx   = tid & 15;
  const int lrow = tid >> 2;        // 0..63
  const int lk   = (tid & 3) * 4;   // 0,4,8,12

  float acc[4][4];
#pragma unroll
  for (int i = 0; i < 4; i++)
#pragma unroll
    for (int j = 0; j < 4; j++) acc[i][j] = 0.f;

  const int mA = m0 + lrow;
  const int nW = n0 + lrow;
  const float* Arow = A + (size_t)mA * K;
  const float* Wrow = W + (size_t)nW * K;
  const bool va = (mA < M);
  const bool vw = (nW < N);

  for (int k0 = 0; k0 < K; k0 += BK) {
#pragma unroll
    for (int j = 0; j < 4; j++) {
      int kk = k0 + lk + j;
      As[lk + j][lrow] = (va && kk < K) ? Arow[kk] : 0.f;
      Ws[lk + j][lrow] = (vw && kk < K) ? Wrow[kk] : 0.f;
    }
    __syncthreads();
#pragma unroll
    for (int kk = 0; kk < BK; kk++) {
      float4 a4 = *reinterpret_cast<const float4*>(&As[kk][ty * 4]);
      float4 b4 = *reinterpret_cast<const float4*>(&Ws[kk][tx * 4]);
      float av[4] = {a4.x, a4.y, a4.z, a4.w};
      float bv[4] = {b4.x, b4.y, b4.z, b4.w};
#pragma unroll
      for (int i = 0; i < 4; i++)
#pragma unroll
        for (int j = 0; j < 4; j++) acc[i][j] += av[i] * bv[j];
    }
    __syncthreads();
  }

#pragma unroll
  for (int i = 0; i < 4; i++) {
    int m = m0 + ty * 4 + i;
#pragma unroll
    for (int j = 0; j < 4; j++) {
      int n = n0 + tx * 4 + j;
      if (m < M && n < N) {
        float v = acc[i][j];
        if (bias) v += bias[n];
        if (FLAGS & 2) v += res[(size_t)m * N + n];
        if (FLAGS & 4) v += pe[(m % NN) * DM_ + n];
        if (FLAGS & 1) v = fmaxf(v, 0.f);
        C[(size_t)m * N + n] = v;
      }
    }
  }
}

// ------------------------------------------------------------------
// 128x128 tile fp32 GEMM for the big projections/FFN.
// REQUIRES M%128==0, N%128==0, K%16==0 (dispatcher enforces).
// Micro-tile: 2x2 blocks of 4x4 at rows {ty*4, 64+ty*4}, cols {tx*4, 64+tx*4}
// -> all LDS reads/writes <=2-way bank-aliased (free).
// ------------------------------------------------------------------
#define LDT2 132

template <int FLAGS>
__global__ __launch_bounds__(256) void gemm_nt128(
    const float* __restrict__ A, const float* __restrict__ W,
    const float* __restrict__ bias, const float* __restrict__ res,
    const float* __restrict__ pe, float* __restrict__ C,
    int M, int K, int N)
{
  __shared__ __align__(16) float As[16][LDT2];
  __shared__ __align__(16) float Ws[16][LDT2];
  const int tid  = threadIdx.x;
  const int m0   = blockIdx.x * 128;
  const int n0   = blockIdx.y * 128;
  const int ty   = tid >> 4;        // 0..15
  const int tx   = tid & 15;        // 0..15
  const int lrow = tid >> 1;        // 0..127
  const int lk   = (tid & 1) * 8;   // 0 or 8

  float acc[2][2][4][4];
#pragma unroll
  for (int a = 0; a < 2; a++)
#pragma unroll
    for (int b = 0; b < 2; b++)
#pragma unroll
      for (int i = 0; i < 4; i++)
#pragma unroll
        for (int j = 0; j < 4; j++) acc[a][b][i][j] = 0.f;

  const float* Arow = A + (size_t)(m0 + lrow) * K + lk;
  const float* Wrow = W + (size_t)(n0 + lrow) * K + lk;

  for (int k0 = 0; k0 < K; k0 += 16) {
    float4 av0 = *reinterpret_cast<const float4*>(Arow + k0);
    float4 av1 = *reinterpret_cast<const float4*>(Arow + k0 + 4);
    float4 wv0 = *reinterpret_cast<const float4*>(Wrow + k0);
    float4 wv1 = *reinterpret_cast<const float4*>(Wrow + k0 + 4);
    __syncthreads();
    As[lk + 0][lrow] = av0.x; As[lk + 1][lrow] = av0.y;
    As[lk + 2][lrow] = av0.z; As[lk + 3][lrow] = av0.w;
    As[lk + 4][lrow] = av1.x; As[lk + 5][lrow] = av1.y;
    As[lk + 6][lrow] = av1.z; As[lk + 7][lrow] = av1.w;
    Ws[lk + 0][lrow] = wv0.x; Ws[lk + 1][lrow] = wv0.y;
    Ws[lk + 2][lrow] = wv0.z; Ws[lk + 3][lrow] = wv0.w;
    Ws[lk + 4][lrow] = wv1.x; Ws[lk + 5][lrow] = wv1.y;
    Ws[lk + 6][lrow] = wv1.z; Ws[lk + 7][lrow] = wv1.w;
    __syncthreads();
#pragma unroll
    for (int kk = 0; kk < 16; kk++) {
      float4 a0 = *reinterpret_cast<const float4*>(&As[kk][ty * 4]);
      float4 a1 = *reinterpret_cast<const float4*>(&As[kk][64 + ty * 4]);
      float4 b0 = *reinterpret_cast<const float4*>(&Ws[kk][tx * 4]);
      float4 b1 = *reinterpret_cast<const float4*>(&Ws[kk][64 + tx * 4]);
      float ar[2][4] = {{a0.x, a0.y, a0.z, a0.w}, {a1.x, a1.y, a1.z, a1.w}};
      float br[2][4] = {{b0.x, b0.y, b0.z, b0.w}, {b1.x, b1.y, b1.z, b1.w}};
#pragma unroll
      for (int a = 0; a < 2; a++)
#pragma unroll
        for (int i = 0; i < 4; i++)
#pragma unroll
          for (int b = 0; b < 2; b++)
#pragma unroll
            for (int j = 0; j < 4; j++)
              acc[a][b][i][j] += ar[a][i] * br[b][j];
    }
  }

#pragma unroll
  for (int a = 0; a < 2; a++)
#pragma unroll
    for (int i = 0; i < 4; i++) {
      int m = m0 + a * 64 + ty * 4 + i;
#pragma unroll
      for (int b = 0; b < 2; b++) {
        int n = n0 + b * 64 + tx * 4;
        float4 v = {acc[a][b][i][0], acc[a][b][i][1], acc[a][b][i][2], acc[a][b][i][3]};
        if (bias) {
          float4 t = *reinterpret_cast<const float4*>(bias + n);
          v.x += t.x; v.y += t.y; v.z += t.z; v.w += t.w;
        }
        if (FLAGS & 2) {
          float4 t = *reinterpret_cast<const float4*>(res + (size_t)m * N + n);
          v.x += t.x; v.y += t.y; v.z += t.z; v.w += t.w;
        }
        if (FLAGS & 4) {
          float4 t = *reinterpret_cast<const float4*>(pe + (size_t)(m % NN) * DM_ + n);
          v.x += t.x; v.y += t.y; v.z += t.z; v.w += t.w;
        }
        if (FLAGS & 1) {
          v.x = fmaxf(v.x, 0.f); v.y = fmaxf(v.y, 0.f);
          v.z = fmaxf(v.z, 0.f); v.w = fmaxf(v.w, 0.f);
        }
        *reinterpret_cast<float4*>(C + (size_t)m * N + n) = v;
      }
    }
}

template <int F>
static void big_gemm(const float* A, const float* W, const float* b,
                     const float* res, const float* pe, float* C,
                     int M, int K, int N, hipStream_t stream) {
  if ((M % 128) == 0 && (N % 128) == 0 && (K % 16) == 0) {
    gemm_nt128<F><<<dim3(M / 128, N / 128), dim3(256), 0, stream>>>(A, W, b, res, pe, C, M, K, N);
  } else {
    gemm_nt<F><<<dim3((M + 63) / 64, (N + 63) / 64), dim3(256), 0, stream>>>(A, W, b, res, pe, C, M, K, N);
  }
}

// ------------------------------------------------------------------
// Deterministic split-K GEMM for the classifier (M small).
// Each z-slice writes its own partial buffer P[z][M][N]; no atomics.
// ------------------------------------------------------------------
__global__ __launch_bounds__(256) void gemm_splitk(
    const float* __restrict__ A, const float* __restrict__ W,
    float* __restrict__ P, int M, int K, int N, int Kc)
{
  __shared__ __align__(16) float As[BK][LDT];
  __shared__ __align__(16) float Ws[BK][LDT];
  const int tid  = threadIdx.x;
  const int m0   = blockIdx.x * BM;
  const int n0   = blockIdx.y * BN;
  const int kb   = blockIdx.z * Kc;
  const int ke   = min(K, kb + Kc);
  const int ty   = tid >> 4;
  const int tx   = tid & 15;
  const int lrow = tid >> 2;
  const int lk   = (tid & 3) * 4;

  float acc[4][4];
#pragma unroll
  for (int i = 0; i < 4; i++)
#pragma unroll
    for (int j = 0; j < 4; j++) acc[i][j] = 0.f;

  const int mA = m0 + lrow;
  const int nW = n0 + lrow;
  const float* Arow = A + (size_t)mA * K;
  const float* Wrow = W + (size_t)nW * K;
  const bool va = (mA < M);
  const bool vw = (nW < N);

  for (int k0 = kb; k0 < ke; k0 += BK) {
#pragma unroll
    for (int j = 0; j < 4; j++) {
      int kk = k0 + lk + j;
      As[lk + j][lrow] = (va && kk < ke) ? Arow[kk] : 0.f;
      Ws[lk + j][lrow] = (vw && kk < ke) ? Wrow[kk] : 0.f;
    }
    __syncthreads();
#pragma unroll
    for (int kk = 0; kk < BK; kk++) {
      float4 a4 = *reinterpret_cast<const float4*>(&As[kk][ty * 4]);
      float4 b4 = *reinterpret_cast<const float4*>(&Ws[kk][tx * 4]);
      float av[4] = {a4.x, a4.y, a4.z, a4.w};
      float bv[4] = {b4.x, b4.y, b4.z, b4.w};
#pragma unroll
      for (int i = 0; i < 4; i++)
#pragma unroll
        for (int j = 0; j < 4; j++) acc[i][j] += av[i] * bv[j];
    }
    __syncthreads();
  }

  float* Pz = P + (size_t)blockIdx.z * M * N;
#pragma unroll
  for (int i = 0; i < 4; i++) {
    int m = m0 + ty * 4 + i;
#pragma unroll
    for (int j = 0; j < 4; j++) {
      int n = n0 + tx * 4 + j;
      if (m < M && n < N) Pz[(size_t)m * N + n] = acc[i][j];
    }
  }
}

// y[m,n] = sum_z P[z][m][n] + bias[n]
__global__ __launch_bounds__(256) void splitk_reduce(
    const float* __restrict__ P, const float* __restrict__ bias,
    float* __restrict__ y, int M, int N)
{
  int i = blockIdx.x * 256 + threadIdx.x;
  if (i >= M * N) return;
  int n = i % N;
  float s = bias[n];
#pragma unroll
  for (int z = 0; z < SPLITK; z++) s += P[(size_t)z * M * N + i];
  y[i] = s;
}

// ------------------------------------------------------------------
// Fused flash-style attention per (b,h).  192 threads, one q-row each.
// ------------------------------------------------------------------
__global__ __launch_bounds__(192) void attn_kernel(
    const float* __restrict__ Q, const float* __restrict__ K,
    const float* __restrict__ V, float* __restrict__ O)
{
  __shared__ __align__(16) float Ks[64][64];
  __shared__ __align__(16) float Vs[64][64];
  const int b = blockIdx.x >> 3;
  const int h = blockIdx.x & 7;
  const int r = threadIdx.x;  // 0..191
  const size_t base = ((size_t)b * NN) * DM_ + h * DH_;

  float q[64], o[64];
  {
    const float4* qp = reinterpret_cast<const float4*>(Q + base + (size_t)r * DM_);
#pragma unroll
    for (int d4 = 0; d4 < 16; d4++) {
      float4 t = qp[d4];
      q[4 * d4 + 0] = t.x; q[4 * d4 + 1] = t.y;
      q[4 * d4 + 2] = t.z; q[4 * d4 + 3] = t.w;
    }
  }
#pragma unroll
  for (int d = 0; d < 64; d++) o[d] = 0.f;
  float m = -3.0e38f, l = 0.f;

  for (int kt = 0; kt < 3; kt++) {
    for (int idx = threadIdx.x; idx < 64 * 16; idx += 192) {
      int row = idx >> 4, c4 = idx & 15;
      const float4* kp = reinterpret_cast<const float4*>(K + base + (size_t)(kt * 64 + row) * DM_);
      const float4* vp = reinterpret_cast<const float4*>(V + base + (size_t)(kt * 64 + row) * DM_);
      reinterpret_cast<float4*>(&Ks[row][0])[c4] = kp[c4];
      reinterpret_cast<float4*>(&Vs[row][0])[c4] = vp[c4];
    }
    __syncthreads();
    for (int j = 0; j < 64; j++) {
      float s = 0.f;
      const float4* kr = reinterpret_cast<const float4*>(&Ks[j][0]);
#pragma unroll
      for (int d4 = 0; d4 < 16; d4++) {
        float4 t = kr[d4];
        s += q[4 * d4 + 0] * t.x + q[4 * d4 + 1] * t.y +
             q[4 * d4 + 2] * t.z + q[4 * d4 + 3] * t.w;
      }
      s *= 0.125f;
      // branchless online-softmax update
      float nm = fmaxf(m, s);
      float corr = expf(m - nm);
      float p = expf(s - nm);
      m = nm;
      l = l * corr + p;
      const float4* vr = reinterpret_cast<const float4*>(&Vs[j][0]);
#pragma unroll
      for (int d4 = 0; d4 < 16; d4++) {
        float4 t = vr[d4];
        o[4 * d4 + 0] = o[4 * d4 + 0] * corr + p * t.x;
        o[4 * d4 + 1] = o[4 * d4 + 1] * corr + p * t.y;
        o[4 * d4 + 2] = o[4 * d4 + 2] * corr + p * t.z;
        o[4 * d4 + 3] = o[4 * d4 + 3] * corr + p * t.w;
      }
    }
    __syncthreads();
  }
  float inv = 1.f / l;
  float* op = O + base + (size_t)r * DM_;
#pragma unroll
  for (int d4 = 0; d4 < 16; d4++) {
    float4 t;
    t.x = o[4 * d4 + 0] * inv; t.y = o[4 * d4 + 1] * inv;
    t.z = o[4 * d4 + 2] * inv; t.w = o[4 * d4 + 3] * inv;
    reinterpret_cast<float4*>(op)[d4] = t;
  }
}

// ------------------------------------------------------------------
// LayerNorm over 512 features; one block (256 thr) per row.
// ------------------------------------------------------------------
__global__ __launch_bounds__(256) void ln_kernel(
    const float* __restrict__ in, float* __restrict__ out,
    const float* __restrict__ g, const float* __restrict__ be)
{
  const size_t row = blockIdx.x;
  const int tid = threadIdx.x;
  float e0 = in[row * DM_ + tid];
  float e1 = in[row * DM_ + 256 + tid];
  __shared__ float red[8];
  float s = e0 + e1;
#pragma unroll
  for (int off = 32; off; off >>= 1) s += __shfl_xor(s, off);
  int wv = tid >> 6, lane = tid & 63;
  if (lane == 0) red[wv] = s;
  __syncthreads();
  float mean = (red[0] + red[1] + red[2] + red[3]) * (1.f / 512.f);
  float d0 = e0 - mean, d1 = e1 - mean;
  float sq = d0 * d0 + d1 * d1;
#pragma unroll
  for (int off = 32; off; off >>= 1) sq += __shfl_xor(sq, off);
  if (lane == 0) red[4 + wv] = sq;
  __syncthreads();
  float var = (red[4] + red[5] + red[6] + red[7]) * (1.f / 512.f);
  float inv = 1.f / sqrtf(var + 1e-5f);
  out[row * DM_ + tid]       = d0 * inv * g[tid] + be[tid];
  out[row * DM_ + 256 + tid] = d1 * inv * g[256 + tid] + be[256 + tid];
}

// ------------------------------------------------------------------
// madj -> nadj (relu(adj + sym)), madj_AS, nadjT (transposed nadj)
// ------------------------------------------------------------------
__global__ __launch_bounds__(1024) void symk(
    const float* __restrict__ madj, const float* __restrict__ adj,
    float* __restrict__ nadj_out, float* __restrict__ as_out,
    float* __restrict__ nadjT)
{
  __shared__ float t1[32][33];
  __shared__ float t2[32][33];
  __shared__ float tn[32][33];
  const int b  = blockIdx.z;
  const int i0 = blockIdx.y * 32, j0 = blockIdx.x * 32;
  const int tx = threadIdx.x, ty = threadIdx.y;
  const size_t bb = (size_t)b * NN * NN;
  t1[ty][tx] = madj[bb + (size_t)(i0 + ty) * NN + j0 + tx];
  t2[ty][tx] = madj[bb + (size_t)(j0 + ty) * NN + i0 + tx];
  __syncthreads();
  float mij = t1[ty][tx], mji = t2[tx][ty];
  float sS = 0.5f * (mij + mji);
  float sA = 0.5f * (mij - mji);
  float na = fmaxf(adj[bb + (size_t)(i0 + ty) * NN + j0 + tx] + sS, 0.f);
  nadj_out[bb + (size_t)(i0 + ty) * NN + j0 + tx] = na;
  as_out[bb + (size_t)(i0 + ty) * NN + j0 + tx]   = sA;
  tn[ty][tx] = na;
  __syncthreads();
  nadjT[bb + (size_t)(j0 + ty) * NN + i0 + tx] = tn[tx][ty];
}

// ------------------------------------------------------------------
// Fused GAT attention
// ------------------------------------------------------------------
__global__ __launch_bounds__(256) void gat_kernel(
    const float* __restrict__ xp, const float* __restrict__ nadjT,
    const float* __restrict__ a_s, const float* __restrict__ a_d,
    const float* __restrict__ bg, float* __restrict__ xg)
{
  __shared__ float xps[NN][33];
  __shared__ float es[2][NN];
  __shared__ float ed[2][NN];
  __shared__ float al[4][2][NN];
  const int b  = blockIdx.x;
  const int qq = blockIdx.y;   // 0..3
  const int tid = threadIdx.x;

  for (int idx = tid; idx < NN * 32; idx += 256) {
    int n = idx >> 5, c = idx & 31;
    xps[n][c] = xp[((size_t)b * NN + n) * 32 + c];
  }
  __syncthreads();
  for (int t = tid; t < 4 * NN; t += 256) {
    int n = t % NN;
    int h = (t / NN) & 1;
    int which = t / (2 * NN);
    const float* av = which ? a_d : a_s;
    float sum = 0.f;
#pragma unroll
    for (int c = 0; c < 16; c++) sum += xps[n][h * 16 + c] * av[h * 16 + c];
    if (which) ed[h][n] = sum; else es[h][n] = sum;
  }
  __syncthreads();

  const int w = tid >> 6, lane = tid & 63;
  for (int dst = qq * 48 + w; dst < qq * 48 + 48; dst += 4) {
    float ed0 = ed[0][dst], ed1 = ed[1][dst];
    float e0[3], e1[3];
    float mx0 = -3e38f, mx1 = -3e38f;
    const float* nrow = nadjT + ((size_t)b * NN + dst) * NN;
#pragma unroll
    for (int s3 = 0; s3 < 3; s3++) {
      int src = lane + 64 * s3;
      bool mk = (nrow[src] > 0.f) || (src == dst);
      float a0 = es[0][src] + ed0; a0 = (a0 > 0.f) ? a0 : 0.2f * a0;
      float a1 = es[1][src] + ed1; a1 = (a1 > 0.f) ? a1 : 0.2f * a1;
      e0[s3] = mk ? a0 : -1e9f;
      e1[s3] = mk ? a1 : -1e9f;
      mx0 = fmaxf(mx0, e0[s3]); mx1 = fmaxf(mx1, e1[s3]);
    }
#pragma unroll
    for (int off = 32; off; off >>= 1) {
      mx0 = fmaxf(mx0, __shfl_xor(mx0, off));
      mx1 = fmaxf(mx1, __shfl_xor(mx1, off));
    }
    float s0 = 0.f, s1 = 0.f, p0[3], p1[3];
#pragma unroll
    for (int s3 = 0; s3 < 3; s3++) {
      p0[s3] = expf(e0[s3] - mx0); s0 += p0[s3];
      p1[s3] = expf(e1[s3] - mx1); s1 += p1[s3];
    }
#pragma unroll
    for (int off = 32; off; off >>= 1) {
      s0 += __shfl_xor(s0, off);
      s1 += __shfl_xor(s1, off);
    }
    float i0 = 1.f / s0, i1 = 1.f / s1;
#pragma unroll
    for (int s3 = 0; s3 < 3; s3++) {
      int src = lane + 64 * s3;
      al[w][0][src] = p0[s3] * i0;
      al[w][1][src] = p1[s3] * i1;
    }
    int half = lane >> 5;
    int hh = (lane >> 4) & 1, cc = lane & 15;
    float acc = 0.f;
    for (int src = half * 96; src < half * 96 + 96; src++) {
      acc += al[w][hh][src] * xps[src][hh * 16 + cc];
    }
    acc += __shfl_xor(acc, 32);
    if (lane < 32) {
      float v = acc + bg[lane];
      xg[((size_t)b * NN + dst) * 32 + lane] = fmaxf(v, 0.f);
    }
  }
}

// ------------------------------------------------------------------
extern "C" void kernel_launch(void* const* d_in, const int* in_sizes, int n_in,
                              void* d_out, int out_size, void* d_ws, size_t ws_size,
                              hipStream_t stream)
{
  const float* x    = (const float*)d_in[0];
  const float* adj  = (const float*)d_in[1];
  const float* W_up = (const float*)d_in[3];
  const float* b_up = (const float*)d_in[4];
  const float* W_lin= (const float*)d_in[5];
  const float* b_lin= (const float*)d_in[6];
  const float* Wq = (const float*)d_in[7];   const float* bq = (const float*)d_in[8];
  const float* Wk = (const float*)d_in[9];   const float* bk = (const float*)d_in[10];
  const float* Wv = (const float*)d_in[11];  const float* bv = (const float*)d_in[12];
  const float* Wo = (const float*)d_in[13];  const float* bo = (const float*)d_in[14];
  const float* g1 = (const float*)d_in[15];  const float* be1= (const float*)d_in[16];
  const float* W1 = (const float*)d_in[17];  const float* b1 = (const float*)d_in[18];
  const float* W2 = (const float*)d_in[19];  const float* b2 = (const float*)d_in[20];
  const float* g2 = (const float*)d_in[21];  const float* be2= (const float*)d_in[22];
  const float* W_map=(const float*)d_in[23]; const float* b_map=(const float*)d_in[24];
  const float* Wg1= (const float*)d_in[25];  const float* as1=(const float*)d_in[26];
  const float* ad1= (const float*)d_in[27];  const float* bg1=(const float*)d_in[28];
  const float* Wg2= (const float*)d_in[29];  const float* as2=(const float*)d_in[30];
  const float* ad2= (const float*)d_in[31];  const float* bg2=(const float*)d_in[32];
  const float* Wg3= (const float*)d_in[33];  const float* as3=(const float*)d_in[34];
  const float* ad3= (const float*)d_in[35];  const float* bg3=(const float*)d_in[36];
  const float* Wcls=(const float*)d_in[37];  const float* bcls=(const float*)d_in[38];

  float* ws = (float*)d_ws;
  const size_t avail = ws_size / 4;
  int CB = 256;
  while (CB > 1) {
    size_t need = 98304ULL + (size_t)CB * (970752ULL + SPLITK * 1000ULL);
    if (need <= avail) break;
    CB >>= 1;
  }

  float* pe   = ws;            size_t off = 98304;
  float* buf0 = ws + off;      off += (size_t)CB * 36864;   // h0 / madj
  float* bh   = ws + off;      off += (size_t)CB * 98304;   // h
  float* bq_  = ws + off;      off += (size_t)CB * 98304;
  float* bk_  = ws + off;      off += (size_t)CB * 98304;   // k / pre-LN scratch
  float* bv_  = ws + off;      off += (size_t)CB * 98304;
  float* bo_  = ws + off;      off += (size_t)CB * 98304;
  float* bff  = ws + off;      off += (size_t)CB * 393216;
  float* bnT  = ws + off;      off += (size_t)CB * 36864;
  float* bgp  = ws + off;      off += (size_t)CB * 6144;
  float* bgg  = ws + off;      off += (size_t)CB * 6144;
  float* bpart= ws + off;      off += (size_t)CB * SPLITK * 1000;

  float* y_out    = (float*)d_out;
  float* nadj_out = y_out + (size_t)BFULL * NCLS;
  float* as_out   = nadj_out + (size_t)BFULL * NN * NN;

  pe_kernel<<<dim3(NN), dim3(256), 0, stream>>>(pe);

  for (int b0 = 0; b0 < BFULL; b0 += CB) {
    const int M1 = CB * NN;
    const float* x_c   = x   + (size_t)b0 * NN * DIN_;
    const float* adj_c = adj + (size_t)b0 * NN * NN;
    dim3 blk(256);
    auto grd = [](int M, int Nc) { return dim3((M + BM - 1) / BM, (Nc + BN - 1) / BN); };

    // transformer branch
    gemm_nt<2><<<grd(M1, NN),  blk, 0, stream>>>(x_c,  W_up,  b_up,  adj_c,   nullptr, buf0, M1, DIN_, NN);
    big_gemm<4>(buf0, W_lin, b_lin, nullptr, pe, bh, M1, NN, DM_, stream);
    big_gemm<0>(bh, Wq, bq, nullptr, nullptr, bq_, M1, DM_, DM_, stream);
    big_gemm<0>(bh, Wk, bk, nullptr, nullptr, bk_, M1, DM_, DM_, stream);
    big_gemm<0>(bh, Wv, bv, nullptr, nullptr, bv_, M1, DM_, DM_, stream);
    attn_kernel<<<dim3(CB * NHD), dim3(NN), 0, stream>>>(bq_, bk_, bv_, bo_);
    big_gemm<2>(bo_, Wo, bo, bh, nullptr, bk_, M1, DM_, DM_, stream);
    ln_kernel<<<dim3(M1), dim3(256), 0, stream>>>(bk_, bh, g1, be1);
    big_gemm<1>(bh,  W1, b1, nullptr, nullptr, bff, M1, DM_, DFF_, stream);
    big_gemm<2>(bff, W2, b2, bh,      nullptr, bk_, M1, DFF_, DM_, stream);
    ln_kernel<<<dim3(M1), dim3(256), 0, stream>>>(bk_, bh, g2, be2);
    gemm_nt<0><<<grd(M1, NN), blk, 0, stream>>>(bh, W_map, b_map, nullptr, nullptr, buf0, M1, DM_, NN);
    symk<<<dim3(6, 6, CB), dim3(32, 32), 0, stream>>>(
        buf0, adj_c,
        nadj_out + (size_t)b0 * NN * NN,
        as_out   + (size_t)b0 * NN * NN,
        bnT);

    // GAT stack (layer 1 input is original x)
    gemm_nt<0><<<grd(M1, GHC), blk, 0, stream>>>(x_c, Wg1, nullptr, nullptr, nullptr, bgp, M1, DIN_, GHC);
    gat_kernel<<<dim3(CB, 4), blk, 0, stream>>>(bgp, bnT, as1, ad1, bg1, bgg);
    gemm_nt<0><<<grd(M1, GHC), blk, 0, stream>>>(bgg, Wg2, nullptr, nullptr, nullptr, bgp, M1, GHC, GHC);
    gat_kernel<<<dim3(CB, 4), blk, 0, stream>>>(bgp, bnT, as2, ad2, bg2, bgg);
    gemm_nt<0><<<grd(M1, GHC), blk, 0, stream>>>(bgg, Wg3, nullptr, nullptr, nullptr, bgp, M1, GHC, GHC);
    gat_kernel<<<dim3(CB, 4), blk, 0, stream>>>(bgp, bnT, as3, ad3, bg3, bgg);

    // classifier: deterministic split-K into partials, then reduce (+bias)
    gemm_splitk<<<dim3((CB + 63) / 64, (NCLS + 63) / 64, SPLITK), blk, 0, stream>>>(
        bgg, Wcls, bpart, CB, NN * GHC, NCLS, 1024);
    splitk_reduce<<<dim3((CB * NCLS + 255) / 256), blk, 0, stream>>>(
        bpart, bcls, y_out + (size_t)b0 * NCLS, CB, NCLS);
  }
}

// Round 5
// 5859.452 us; speedup vs baseline: 1.2112x; 1.2112x over previous
//
#include <hip/hip_runtime.h>
#include <math.h>

#define NN   192
#define DIN_ 67
#define DM_  512
#define NHD  8
#define DFF_ 2048
#define GHC  32
#define NCLS 1000
#define BFULL 256
#define SPLITK 6

typedef __attribute__((ext_vector_type(8))) short s16x8;
typedef __attribute__((ext_vector_type(4))) float f32x4;

__device__ __forceinline__ f32x4 mfma16(s16x8 a, s16x8 b, f32x4 c) {
  return __builtin_amdgcn_mfma_f32_16x16x32_bf16(a, b, c, 0, 0, 0);
}

__device__ __forceinline__ void gload16(const short* g, short* l) {
  __builtin_amdgcn_global_load_lds(
      (const __attribute__((address_space(1))) unsigned int*)g,
      (__attribute__((address_space(3))) unsigned int*)l, 16, 0, 0);
}

__device__ __forceinline__ void split1(float f, short& h, short& l) {
  unsigned u = __float_as_uint(f);
  unsigned hr = (u + 0x7fffu + ((u >> 16) & 1u)) >> 16;
  h = (short)hr;
  float hf = __uint_as_float(hr << 16);
  float d = f - hf;
  unsigned ud = __float_as_uint(d);
  l = (short)((ud + 0x7fffu + ((ud >> 16) & 1u)) >> 16);
}

__device__ __forceinline__ void split4(float4 v, short4& h, short4& l) {
  split1(v.x, h.x, l.x); split1(v.y, h.y, l.y);
  split1(v.z, h.z, l.z); split1(v.w, h.w, l.w);
}

// ------------------------------------------------------------------
__global__ void pe_kernel(float* __restrict__ pe) {
  int n = blockIdx.x;
  int i = threadIdx.x;
  double div = exp((double)(2 * i) * (-log(10000.0) / (double)DM_));
  double a = (double)n * div;
  pe[n * DM_ + 2 * i]     = (float)sin(a);
  pe[n * DM_ + 2 * i + 1] = (float)cos(a);
}

// fp32 -> bf16 hi/lo, flat vectorized
__global__ __launch_bounds__(256) void cvt_split(
    const float* __restrict__ x, short* __restrict__ hi,
    short* __restrict__ lo, int n4)
{
  int i = blockIdx.x * 256 + threadIdx.x;
  if (i >= n4) return;
  float4 v = reinterpret_cast<const float4*>(x)[i];
  short4 h, L; split4(v, h, L);
  reinterpret_cast<short4*>(hi)[i] = h;
  reinterpret_cast<short4*>(lo)[i] = L;
}

// weight cvt with row padding (rows >= rows are zero)
__global__ __launch_bounds__(256) void cvt_w(
    const float* __restrict__ w, short* __restrict__ hi,
    short* __restrict__ lo, int rows, int K)
{
  int r = blockIdx.y;
  int c4 = blockIdx.x * 256 + threadIdx.x;
  if (c4 * 4 >= K) return;
  float4 v = make_float4(0.f, 0.f, 0.f, 0.f);
  if (r < rows) v = reinterpret_cast<const float4*>(w + (size_t)r * K)[c4];
  short4 h, L; split4(v, h, L);
  reinterpret_cast<short4*>(hi + (size_t)r * K)[c4] = h;
  reinterpret_cast<short4*>(lo + (size_t)r * K)[c4] = L;
}

__global__ void pack_bias(const float* a, const float* b, const float* c, float* o) {
  int i = blockIdx.x * 256 + threadIdx.x;
  if (i < 512) o[i] = a[i];
  else if (i < 1024) o[i] = b[i - 512];
  else if (i < 1536) o[i] = c[i - 1024];
}

// ------------------------------------------------------------------
// Split-bf16 MFMA GEMM: C[M,Nout] = act(A @ W^T + bias [+res] [+pe])
// A = Ahi+Alo [M,K] bf16, W = Whi+Wlo [Npad,K] bf16 (Npad = gridDim.y*128)
// 128x128 tile, BK=64, 4 waves 2x2, each wave 64x64 (4x4 frags of 16x16x32).
// LDS: 4 linear tiles [128][64]bf16, XOR-swizzled slots (slot ^= row&7) so
// global_load_lds (linear dest) + ds_read_b128 frags are conflict-free.
// FLAGS: 1 relu, 2 +res, 4 +pe
// ------------------------------------------------------------------
template <int FLAGS>
__global__ __launch_bounds__(256, 2) void gemm_mfma(
    const short* __restrict__ Ahi, const short* __restrict__ Alo,
    const short* __restrict__ Whi, const short* __restrict__ Wlo,
    const float* __restrict__ bias, const float* __restrict__ res,
    const float* __restrict__ pe, float* __restrict__ C,
    int K, int Nout)
{
  __shared__ __align__(16) short lds[4 * 8192];
  const int tid = threadIdx.x;
  const int l = tid & 63, w = tid >> 6;
  const int m0 = blockIdx.x * 128, n0 = blockIdx.y * 128;
  const int wm = w >> 1, wn = w & 1;
  const int lane_r = l & 15, lane_hi = l >> 4, lx = l & 7;

  // staging: wave w stages rows [w*32, w*32+32) of each tile in 4 issues.
  // issue j covers rows w*32+j*8 .. +8; lane l -> row +(l>>3), phys slot l&7,
  // logical k-chunk (l&7)^(l>>3)  (row&7 == l>>3).
  const int srow = w * 32 + (l >> 3);
  const int slog = (l & 7) ^ (l >> 3);
  size_t aoff[4], woff[4];
  int loff[4];
#pragma unroll
  for (int j = 0; j < 4; j++) {
    aoff[j] = (size_t)(m0 + srow + j * 8) * K + slog * 8;
    woff[j] = (size_t)(n0 + srow + j * 8) * K + slog * 8;
    loff[j] = (w * 32 + j * 8) * 64;
  }

  f32x4 acc[4][4];
#pragma unroll
  for (int a = 0; a < 4; a++)
#pragma unroll
    for (int b = 0; b < 4; b++) acc[a][b] = (f32x4){0.f, 0.f, 0.f, 0.f};

  for (int k0 = 0; k0 < K; k0 += 64) {
#pragma unroll
    for (int j = 0; j < 4; j++) {
      gload16(Ahi + aoff[j] + k0, &lds[0 * 8192 + loff[j]]);
      gload16(Alo + aoff[j] + k0, &lds[1 * 8192 + loff[j]]);
      gload16(Whi + woff[j] + k0, &lds[2 * 8192 + loff[j]]);
      gload16(Wlo + woff[j] + k0, &lds[3 * 8192 + loff[j]]);
    }
    __syncthreads();   // drains vmcnt(0), then barrier
#pragma unroll
    for (int ks = 0; ks < 2; ks++) {
      const int ps = (((ks << 2) | lane_hi) ^ lx) << 3;
      s16x8 ah[4], al[4], bh[4], bl[4];
#pragma unroll
      for (int mf = 0; mf < 4; mf++) {
        int off = (wm * 64 + mf * 16 + lane_r) * 64 + ps;
        ah[mf] = *reinterpret_cast<const s16x8*>(&lds[0 * 8192 + off]);
        al[mf] = *reinterpret_cast<const s16x8*>(&lds[1 * 8192 + off]);
      }
#pragma unroll
      for (int nf = 0; nf < 4; nf++) {
        int off = (wn * 64 + nf * 16 + lane_r) * 64 + ps;
        bh[nf] = *reinterpret_cast<const s16x8*>(&lds[2 * 8192 + off]);
        bl[nf] = *reinterpret_cast<const s16x8*>(&lds[3 * 8192 + off]);
      }
#pragma unroll
      for (int mf = 0; mf < 4; mf++)
#pragma unroll
        for (int nf = 0; nf < 4; nf++) {
          acc[mf][nf] = mfma16(ah[mf], bh[nf], acc[mf][nf]);
          acc[mf][nf] = mfma16(ah[mf], bl[nf], acc[mf][nf]);
          acc[mf][nf] = mfma16(al[mf], bh[nf], acc[mf][nf]);
        }
    }
    __syncthreads();
  }

  // epilogue: D frag -> m = base + (l>>4)*4 + j, n = base + (l&15)
#pragma unroll
  for (int mf = 0; mf < 4; mf++)
#pragma unroll
    for (int nf = 0; nf < 4; nf++) {
      int n = n0 + wn * 64 + nf * 16 + lane_r;
      if (n >= Nout) continue;
      int mb = m0 + wm * 64 + mf * 16 + lane_hi * 4;
      float bn = bias ? bias[n] : 0.f;
#pragma unroll
      for (int j = 0; j < 4; j++) {
        int m = mb + j;
        float v = acc[mf][nf][j] + bn;
        if (FLAGS & 2) v += res[(size_t)m * Nout + n];
        if (FLAGS & 4) v += pe[(m % NN) * DM_ + n];
        if (FLAGS & 1) v = fmaxf(v, 0.f);
        C[(size_t)m * Nout + n] = v;
      }
    }
}

// ------------------------------------------------------------------
// fp32 64x64 GEMM (small/odd shapes): C = act(A @ W^T + bias + extra)
// ------------------------------------------------------------------
#define BM 64
#define BN 64
#define BK 16
#define LDT 68

template <int FLAGS>
__global__ __launch_bounds__(256) void gemm_nt(
    const float* __restrict__ A, const float* __restrict__ W,
    const float* __restrict__ bias, const float* __restrict__ res,
    float* __restrict__ C, int M, int K, int N)
{
  __shared__ __align__(16) float As[BK][LDT];
  __shared__ __align__(16) float Ws[BK][LDT];
  const int tid  = threadIdx.x;
  const int m0   = blockIdx.x * BM;
  const int n0   = blockIdx.y * BN;
  const int ty   = tid >> 4;
  const int tx   = tid & 15;
  const int lrow = tid >> 2;
  const int lk   = (tid & 3) * 4;

  float acc[4][4];
#pragma unroll
  for (int i = 0; i < 4; i++)
#pragma unroll
    for (int j = 0; j < 4; j++) acc[i][j] = 0.f;

  const int mA = m0 + lrow;
  const int nW = n0 + lrow;
  const float* Arow = A + (size_t)mA * K;
  const float* Wrow = W + (size_t)nW * K;
  const bool va = (mA < M);
  const bool vw = (nW < N);

  for (int k0 = 0; k0 < K; k0 += BK) {
#pragma unroll
    for (int j = 0; j < 4; j++) {
      int kk = k0 + lk + j;
      As[lk + j][lrow] = (va && kk < K) ? Arow[kk] : 0.f;
      Ws[lk + j][lrow] = (vw && kk < K) ? Wrow[kk] : 0.f;
    }
    __syncthreads();
#pragma unroll
    for (int kk = 0; kk < BK; kk++) {
      float4 a4 = *reinterpret_cast<const float4*>(&As[kk][ty * 4]);
      float4 b4 = *reinterpret_cast<const float4*>(&Ws[kk][tx * 4]);
      float av[4] = {a4.x, a4.y, a4.z, a4.w};
      float bv[4] = {b4.x, b4.y, b4.z, b4.w};
#pragma unroll
      for (int i = 0; i < 4; i++)
#pragma unroll
        for (int j = 0; j < 4; j++) acc[i][j] += av[i] * bv[j];
    }
    __syncthreads();
  }

#pragma unroll
  for (int i = 0; i < 4; i++) {
    int m = m0 + ty * 4 + i;
#pragma unroll
    for (int j = 0; j < 4; j++) {
      int n = n0 + tx * 4 + j;
      if (m < M && n < N) {
        float v = acc[i][j];
        if (bias) v += bias[n];
        if (FLAGS & 2) v += res[(size_t)m * N + n];
        if (FLAGS & 1) v = fmaxf(v, 0.f);
        C[(size_t)m * N + n] = v;
      }
    }
  }
}

// ------------------------------------------------------------------
// Deterministic split-K classifier GEMM + reduce
// ------------------------------------------------------------------
__global__ __launch_bounds__(256) void gemm_splitk(
    const float* __restrict__ A, const float* __restrict__ W,
    float* __restrict__ P, int M, int K, int N, int Kc)
{
  __shared__ __align__(16) float As[BK][LDT];
  __shared__ __align__(16) float Ws[BK][LDT];
  const int tid  = threadIdx.x;
  const int m0   = blockIdx.x * BM;
  const int n0   = blockIdx.y * BN;
  const int kb   = blockIdx.z * Kc;
  const int ke   = min(K, kb + Kc);
  const int ty   = tid >> 4;
  const int tx   = tid & 15;
  const int lrow = tid >> 2;
  const int lk   = (tid & 3) * 4;

  float acc[4][4];
#pragma unroll
  for (int i = 0; i < 4; i++)
#pragma unroll
    for (int j = 0; j < 4; j++) acc[i][j] = 0.f;

  const int mA = m0 + lrow;
  const int nW = n0 + lrow;
  const float* Arow = A + (size_t)mA * K;
  const float* Wrow = W + (size_t)nW * K;
  const bool va = (mA < M);
  const bool vw = (nW < N);

  for (int k0 = kb; k0 < ke; k0 += BK) {
#pragma unroll
    for (int j = 0; j < 4; j++) {
      int kk = k0 + lk + j;
      As[lk + j][lrow] = (va && kk < ke) ? Arow[kk] : 0.f;
      Ws[lk + j][lrow] = (vw && kk < ke) ? Wrow[kk] : 0.f;
    }
    __syncthreads();
#pragma unroll
    for (int kk = 0; kk < BK; kk++) {
      float4 a4 = *reinterpret_cast<const float4*>(&As[kk][ty * 4]);
      float4 b4 = *reinterpret_cast<const float4*>(&Ws[kk][tx * 4]);
      float av[4] = {a4.x, a4.y, a4.z, a4.w};
      float bv[4] = {b4.x, b4.y, b4.z, b4.w};
#pragma unroll
      for (int i = 0; i < 4; i++)
#pragma unroll
        for (int j = 0; j < 4; j++) acc[i][j] += av[i] * bv[j];
    }
    __syncthreads();
  }

  float* Pz = P + (size_t)blockIdx.z * M * N;
#pragma unroll
  for (int i = 0; i < 4; i++) {
    int m = m0 + ty * 4 + i;
#pragma unroll
    for (int j = 0; j < 4; j++) {
      int n = n0 + tx * 4 + j;
      if (m < M && n < N) Pz[(size_t)m * N + n] = acc[i][j];
    }
  }
}

__global__ __launch_bounds__(256) void splitk_reduce(
    const float* __restrict__ P, const float* __restrict__ bias,
    float* __restrict__ y, int M, int N)
{
  int i = blockIdx.x * 256 + threadIdx.x;
  if (i >= M * N) return;
  int n = i % N;
  float s = bias[n];
#pragma unroll
  for (int z = 0; z < SPLITK; z++) s += P[(size_t)z * M * N + i];
  y[i] = s;
}

// ------------------------------------------------------------------
// Flash attention per (b,h); QKV fused layout [M1,1536] (q|k|v)
// ------------------------------------------------------------------
__global__ __launch_bounds__(192) void attn_kernel(
    const float* __restrict__ QKV, float* __restrict__ O)
{
  __shared__ __align__(16) float Ks[64][64];
  __shared__ __align__(16) float Vs[64][64];
  const int b = blockIdx.x >> 3;
  const int h = blockIdx.x & 7;
  const int r = threadIdx.x;
  const float* Qb = QKV + (size_t)(b * NN) * 1536 + h * 64;

  float q[64], o[64];
  {
    const float4* qp = reinterpret_cast<const float4*>(Qb + (size_t)r * 1536);
#pragma unroll
    for (int d4 = 0; d4 < 16; d4++) {
      float4 t = qp[d4];
      q[4 * d4 + 0] = t.x; q[4 * d4 + 1] = t.y;
      q[4 * d4 + 2] = t.z; q[4 * d4 + 3] = t.w;
    }
  }
#pragma unroll
  for (int d = 0; d < 64; d++) o[d] = 0.f;
  float m = -3.0e38f, l = 0.f;

  for (int kt = 0; kt < 3; kt++) {
    for (int idx = threadIdx.x; idx < 64 * 16; idx += 192) {
      int row = idx >> 4, c4 = idx & 15;
      const float4* kp = reinterpret_cast<const float4*>(Qb + 512 + (size_t)(kt * 64 + row) * 1536);
      const float4* vp = reinterpret_cast<const float4*>(Qb + 1024 + (size_t)(kt * 64 + row) * 1536);
      reinterpret_cast<float4*>(&Ks[row][0])[c4] = kp[c4];
      reinterpret_cast<float4*>(&Vs[row][0])[c4] = vp[c4];
    }
    __syncthreads();
    for (int j = 0; j < 64; j++) {
      float s = 0.f;
      const float4* kr = reinterpret_cast<const float4*>(&Ks[j][0]);
#pragma unroll
      for (int d4 = 0; d4 < 16; d4++) {
        float4 t = kr[d4];
        s += q[4 * d4 + 0] * t.x + q[4 * d4 + 1] * t.y +
             q[4 * d4 + 2] * t.z + q[4 * d4 + 3] * t.w;
      }
      s *= 0.125f;
      float nm = fmaxf(m, s);
      float corr = expf(m - nm);
      float p = expf(s - nm);
      m = nm;
      l = l * corr + p;
      const float4* vr = reinterpret_cast<const float4*>(&Vs[j][0]);
#pragma unroll
      for (int d4 = 0; d4 < 16; d4++) {
        float4 t = vr[d4];
        o[4 * d4 + 0] = o[4 * d4 + 0] * corr + p * t.x;
        o[4 * d4 + 1] = o[4 * d4 + 1] * corr + p * t.y;
        o[4 * d4 + 2] = o[4 * d4 + 2] * corr + p * t.z;
        o[4 * d4 + 3] = o[4 * d4 + 3] * corr + p * t.w;
      }
    }
    __syncthreads();
  }
  float inv = 1.f / l;
  float* op = O + (size_t)(b * NN + r) * DM_ + h * 64;
#pragma unroll
  for (int d4 = 0; d4 < 16; d4++) {
    float4 t;
    t.x = o[4 * d4 + 0] * inv; t.y = o[4 * d4 + 1] * inv;
    t.z = o[4 * d4 + 2] * inv; t.w = o[4 * d4 + 3] * inv;
    reinterpret_cast<float4*>(op)[d4] = t;
  }
}

// ------------------------------------------------------------------
__global__ __launch_bounds__(256) void ln_kernel(
    const float* __restrict__ in, float* __restrict__ out,
    const float* __restrict__ g, const float* __restrict__ be)
{
  const size_t row = blockIdx.x;
  const int tid = threadIdx.x;
  float e0 = in[row * DM_ + tid];
  float e1 = in[row * DM_ + 256 + tid];
  __shared__ float red[8];
  float s = e0 + e1;
#pragma unroll
  for (int off = 32; off; off >>= 1) s += __shfl_xor(s, off);
  int wv = tid >> 6, lane = tid & 63;
  if (lane == 0) red[wv] = s;
  __syncthreads();
  float mean = (red[0] + red[1] + red[2] + red[3]) * (1.f / 512.f);
  float d0 = e0 - mean, d1 = e1 - mean;
  float sq = d0 * d0 + d1 * d1;
#pragma unroll
  for (int off = 32; off; off >>= 1) sq += __shfl_xor(sq, off);
  if (lane == 0) red[4 + wv] = sq;
  __syncthreads();
  float var = (red[4] + red[5] + red[6] + red[7]) * (1.f / 512.f);
  float inv = 1.f / sqrtf(var + 1e-5f);
  out[row * DM_ + tid]       = d0 * inv * g[tid] + be[tid];
  out[row * DM_ + 256 + tid] = d1 * inv * g[256 + tid] + be[256 + tid];
}

// ------------------------------------------------------------------
__global__ __launch_bounds__(1024) void symk(
    const float* __restrict__ madj, const float* __restrict__ adj,
    float* __restrict__ nadj_out, float* __restrict__ as_out,
    float* __restrict__ nadjT)
{
  __shared__ float t1[32][33];
  __shared__ float t2[32][33];
  __shared__ float tn[32][33];
  const int b  = blockIdx.z;
  const int i0 = blockIdx.y * 32, j0 = blockIdx.x * 32;
  const int tx = threadIdx.x, ty = threadIdx.y;
  const size_t bb = (size_t)b * NN * NN;
  t1[ty][tx] = madj[bb + (size_t)(i0 + ty) * NN + j0 + tx];
  t2[ty][tx] = madj[bb + (size_t)(j0 + ty) * NN + i0 + tx];
  __syncthreads();
  float mij = t1[ty][tx], mji = t2[tx][ty];
  float sS = 0.5f * (mij + mji);
  float sA = 0.5f * (mij - mji);
  float na = fmaxf(adj[bb + (size_t)(i0 + ty) * NN + j0 + tx] + sS, 0.f);
  nadj_out[bb + (size_t)(i0 + ty) * NN + j0 + tx] = na;
  as_out[bb + (size_t)(i0 + ty) * NN + j0 + tx]   = sA;
  tn[ty][tx] = na;
  __syncthreads();
  nadjT[bb + (size_t)(j0 + ty) * NN + i0 + tx] = tn[tx][ty];
}

// ------------------------------------------------------------------
__global__ __launch_bounds__(256) void gat_kernel(
    const float* __restrict__ xp, const float* __restrict__ nadjT,
    const float* __restrict__ a_s, const float* __restrict__ a_d,
    const float* __restrict__ bg, float* __restrict__ xg)
{
  __shared__ float xps[NN][33];
  __shared__ float es[2][NN];
  __shared__ float ed[2][NN];
  __shared__ float al[4][2][NN];
  const int b  = blockIdx.x;
  const int qq = blockIdx.y;
  const int tid = threadIdx.x;

  for (int idx = tid; idx < NN * 32; idx += 256) {
    int n = idx >> 5, c = idx & 31;
    xps[n][c] = xp[((size_t)b * NN + n) * 32 + c];
  }
  __syncthreads();
  for (int t = tid; t < 4 * NN; t += 256) {
    int n = t % NN;
    int h = (t / NN) & 1;
    int which = t / (2 * NN);
    const float* av = which ? a_d : a_s;
    float sum = 0.f;
#pragma unroll
    for (int c = 0; c < 16; c++) sum += xps[n][h * 16 + c] * av[h * 16 + c];
    if (which) ed[h][n] = sum; else es[h][n] = sum;
  }
  __syncthreads();

  const int w = tid >> 6, lane = tid & 63;
  for (int dst = qq * 48 + w; dst < qq * 48 + 48; dst += 4) {
    float ed0 = ed[0][dst], ed1 = ed[1][dst];
    float e0[3], e1[3];
    float mx0 = -3e38f, mx1 = -3e38f;
    const float* nrow = nadjT + ((size_t)b * NN + dst) * NN;
#pragma unroll
    for (int s3 = 0; s3 < 3; s3++) {
      int src = lane + 64 * s3;
      bool mk = (nrow[src] > 0.f) || (src == dst);
      float a0 = es[0][src] + ed0; a0 = (a0 > 0.f) ? a0 : 0.2f * a0;
      float a1 = es[1][src] + ed1; a1 = (a1 > 0.f) ? a1 : 0.2f * a1;
      e0[s3] = mk ? a0 : -1e9f;
      e1[s3] = mk ? a1 : -1e9f;
      mx0 = fmaxf(mx0, e0[s3]); mx1 = fmaxf(mx1, e1[s3]);
    }
#pragma unroll
    for (int off = 32; off; off >>= 1) {
      mx0 = fmaxf(mx0, __shfl_xor(mx0, off));
      mx1 = fmaxf(mx1, __shfl_xor(mx1, off));
    }
    float s0 = 0.f, s1 = 0.f, p0[3], p1[3];
#pragma unroll
    for (int s3 = 0; s3 < 3; s3++) {
      p0[s3] = expf(e0[s3] - mx0); s0 += p0[s3];
      p1[s3] = expf(e1[s3] - mx1); s1 += p1[s3];
    }
#pragma unroll
    for (int off = 32; off; off >>= 1) {
      s0 += __shfl_xor(s0, off);
      s1 += __shfl_xor(s1, off);
    }
    float i0 = 1.f / s0, i1 = 1.f / s1;
#pragma unroll
    for (int s3 = 0; s3 < 3; s3++) {
      int src = lane + 64 * s3;
      al[w][0][src] = p0[s3] * i0;
      al[w][1][src] = p1[s3] * i1;
    }
    int half = lane >> 5;
    int hh = (lane >> 4) & 1, cc = lane & 15;
    float acc = 0.f;
    for (int src = half * 96; src < half * 96 + 96; src++) {
      acc += al[w][hh][src] * xps[src][hh * 16 + cc];
    }
    acc += __shfl_xor(acc, 32);
    if (lane < 32) {
      float v = acc + bg[lane];
      xg[((size_t)b * NN + dst) * 32 + lane] = fmaxf(v, 0.f);
    }
  }
}

// ------------------------------------------------------------------
extern "C" void kernel_launch(void* const* d_in, const int* in_sizes, int n_in,
                              void* d_out, int out_size, void* d_ws, size_t ws_size,
                              hipStream_t stream)
{
  const float* x    = (const float*)d_in[0];
  const float* adj  = (const float*)d_in[1];
  const float* W_up = (const float*)d_in[3];
  const float* b_up = (const float*)d_in[4];
  const float* W_lin= (const float*)d_in[5];
  const float* b_lin= (const float*)d_in[6];
  const float* Wq = (const float*)d_in[7];   const float* bq = (const float*)d_in[8];
  const float* Wk = (const float*)d_in[9];   const float* bk = (const float*)d_in[10];
  const float* Wv = (const float*)d_in[11];  const float* bv = (const float*)d_in[12];
  const float* Wo = (const float*)d_in[13];  const float* bo = (const float*)d_in[14];
  const float* g1 = (const float*)d_in[15];  const float* be1= (const float*)d_in[16];
  const float* W1 = (const float*)d_in[17];  const float* b1 = (const float*)d_in[18];
  const float* W2 = (const float*)d_in[19];  const float* b2 = (const float*)d_in[20];
  const float* g2 = (const float*)d_in[21];  const float* be2= (const float*)d_in[22];
  const float* W_map=(const float*)d_in[23]; const float* b_map=(const float*)d_in[24];
  const float* Wg1= (const float*)d_in[25];  const float* as1=(const float*)d_in[26];
  const float* ad1= (const float*)d_in[27];  const float* bg1=(const float*)d_in[28];
  const float* Wg2= (const float*)d_in[29];  const float* as2=(const float*)d_in[30];
  const float* ad2= (const float*)d_in[31];  const float* bg2=(const float*)d_in[32];
  const float* Wg3= (const float*)d_in[33];  const float* as3=(const float*)d_in[34];
  const float* ad3= (const float*)d_in[35];  const float* bg3=(const float*)d_in[36];
  const float* Wcls=(const float*)d_in[37];  const float* bcls=(const float*)d_in[38];

  float* ws = (float*)d_ws;
  const size_t avail = ws_size / 4;
  int CB = 256;
  while (CB > 2 && 3474944ULL + (size_t)CB * 1468272ULL > avail) CB >>= 1;

  size_t off = 0;
  float* pe   = ws;                      off += 98304;
  short* wsh  = (short*)(ws + off);      off += 3375104;   // hi/lo weights
  float* qkvb = ws + off;                off += 1536;
  float* buf0 = ws + off;                off += (size_t)CB * 36864;
  float* bh   = ws + off;                off += (size_t)CB * 98304;
  float* bqkv = ws + off;                off += (size_t)CB * 294912;
  float* bsc  = ws + off;                off += (size_t)CB * 98304;
  float* bo_  = ws + off;                off += (size_t)CB * 98304;
  float* bff  = ws + off;                off += (size_t)CB * 393216;
  float* bnT  = ws + off;                off += (size_t)CB * 36864;
  float* bgp  = ws + off;                off += (size_t)CB * 6144;
  float* bgg  = ws + off;                off += (size_t)CB * 6144;
  short* act_hi = (short*)(ws + off);    off += (size_t)CB * 196608;
  short* act_lo = (short*)(ws + off);    off += (size_t)CB * 196608;
  float* bpart  = ws + off;              off += (size_t)CB * SPLITK * 1000;

  // weight hi/lo sub-buffers (shorts)
  short* Wlin_hi = wsh;                     short* Wlin_lo = Wlin_hi + 98304;
  short* Wqkv_hi = Wlin_lo + 98304;         short* Wqkv_lo = Wqkv_hi + 786432;
  short* Wo_hi   = Wqkv_lo + 786432;        short* Wo_lo   = Wo_hi + 262144;
  short* W1_hi   = Wo_lo + 262144;          short* W1_lo   = W1_hi + 1048576;
  short* W2_hi   = W1_lo + 1048576;         short* W2_lo   = W2_hi + 1048576;
  short* Wm_hi   = W2_lo + 1048576;         short* Wm_lo   = Wm_hi + 131072;

  float* y_out    = (float*)d_out;
  float* nadj_out = y_out + (size_t)BFULL * NCLS;
  float* as_out   = nadj_out + (size_t)BFULL * NN * NN;

  pe_kernel<<<dim3(NN), dim3(256), 0, stream>>>(pe);
  pack_bias<<<dim3(6), dim3(256), 0, stream>>>(bq, bk, bv, qkvb);
  auto CW = [&](const float* w, short* hi, short* lo, int rows, int rpad, int K) {
    cvt_w<<<dim3((K / 4 + 255) / 256, rpad), dim3(256), 0, stream>>>(w, hi, lo, rows, K);
  };
  CW(W_lin, Wlin_hi, Wlin_lo, 512, 512, 192);
  CW(Wq, Wqkv_hi,          Wqkv_lo,          512, 512, 512);
  CW(Wk, Wqkv_hi + 262144, Wqkv_lo + 262144, 512, 512, 512);
  CW(Wv, Wqkv_hi + 524288, Wqkv_lo + 524288, 512, 512, 512);
  CW(Wo, Wo_hi, Wo_lo, 512, 512, 512);
  CW(W1, W1_hi, W1_lo, 2048, 2048, 512);
  CW(W2, W2_hi, W2_lo, 512, 512, 2048);
  CW(W_map, Wm_hi, Wm_lo, 192, 256, 512);

  for (int b0 = 0; b0 < BFULL; b0 += CB) {
    const int M1 = CB * NN;
    const float* x_c   = x   + (size_t)b0 * NN * DIN_;
    const float* adj_c = adj + (size_t)b0 * NN * NN;
    dim3 blk(256);
    auto cvt = [&](const float* src, int nelem) {
      cvt_split<<<dim3((nelem / 4 + 255) / 256), blk, 0, stream>>>(src, act_hi, act_lo, nelem / 4);
    };
    auto MF = [&](int F, const short* Wh, const short* Wl, const float* bias_,
                  const float* res_, const float* pe_, float* C, int K, int Npad, int Nout) {
      dim3 g(M1 / 128, Npad / 128);
      switch (F) {
        case 0: gemm_mfma<0><<<g, blk, 0, stream>>>(act_hi, act_lo, Wh, Wl, bias_, res_, pe_, C, K, Nout); break;
        case 1: gemm_mfma<1><<<g, blk, 0, stream>>>(act_hi, act_lo, Wh, Wl, bias_, res_, pe_, C, K, Nout); break;
        case 2: gemm_mfma<2><<<g, blk, 0, stream>>>(act_hi, act_lo, Wh, Wl, bias_, res_, pe_, C, K, Nout); break;
        case 4: gemm_mfma<4><<<g, blk, 0, stream>>>(act_hi, act_lo, Wh, Wl, bias_, res_, pe_, C, K, Nout); break;
      }
    };

    // transformer branch
    gemm_nt<2><<<dim3(M1 / 64, 3), blk, 0, stream>>>(x_c, W_up, b_up, adj_c, buf0, M1, DIN_, NN);
    cvt(buf0, M1 * NN);
    MF(4, Wlin_hi, Wlin_lo, b_lin, nullptr, pe, bh, NN, DM_, DM_);
    cvt(bh, M1 * DM_);
    MF(0, Wqkv_hi, Wqkv_lo, qkvb, nullptr, nullptr, bqkv, DM_, 1536, 1536);
    attn_kernel<<<dim3(CB * NHD), dim3(NN), 0, stream>>>(bqkv, bo_);
    cvt(bo_, M1 * DM_);
    MF(2, Wo_hi, Wo_lo, bo, bh, nullptr, bsc, DM_, DM_, DM_);
    ln_kernel<<<dim3(M1), blk, 0, stream>>>(bsc, bh, g1, be1);
    cvt(bh, M1 * DM_);
    MF(1, W1_hi, W1_lo, b1, nullptr, nullptr, bff, DM_, DFF_, DFF_);
    cvt(bff, M1 * DFF_);
    MF(2, W2_hi, W2_lo, b2, bh, nullptr, bsc, DFF_, DM_, DM_);
    ln_kernel<<<dim3(M1), blk, 0, stream>>>(bsc, bh, g2, be2);
    cvt(bh, M1 * DM_);
    MF(0, Wm_hi, Wm_lo, b_map, nullptr, nullptr, buf0, DM_, 256, NN);
    symk<<<dim3(6, 6, CB), dim3(32, 32), 0, stream>>>(
        buf0, adj_c,
        nadj_out + (size_t)b0 * NN * NN,
        as_out   + (size_t)b0 * NN * NN,
        bnT);

    // GAT stack
    gemm_nt<0><<<dim3(M1 / 64, 1), blk, 0, stream>>>(x_c, Wg1, nullptr, nullptr, bgp, M1, DIN_, GHC);
    gat_kernel<<<dim3(CB, 4), blk, 0, stream>>>(bgp, bnT, as1, ad1, bg1, bgg);
    gemm_nt<0><<<dim3(M1 / 64, 1), blk, 0, stream>>>(bgg, Wg2, nullptr, nullptr, bgp, M1, GHC, GHC);
    gat_kernel<<<dim3(CB, 4), blk, 0, stream>>>(bgp, bnT, as2, ad2, bg2, bgg);
    gemm_nt<0><<<dim3(M1 / 64, 1), blk, 0, stream>>>(bgg, Wg3, nullptr, nullptr, bgp, M1, GHC, GHC);
    gat_kernel<<<dim3(CB, 4), blk, 0, stream>>>(bgp, bnT, as3, ad3, bg3, bgg);

    // classifier
    gemm_splitk<<<dim3((CB + 63) / 64, (NCLS + 63) / 64, SPLITK), blk, 0, stream>>>(
        bgg, Wcls, bpart, CB, NN * GHC, NCLS, 1024);
    splitk_reduce<<<dim3((CB * NCLS + 255) / 256), blk, 0, stream>>>(
        bpart, bcls, y_out + (size_t)b0 * NCLS, CB, NCLS);
  }
}

// Round 6
// 3544.140 us; speedup vs baseline: 2.0024x; 1.6533x over previous
//
#include <hip/hip_runtime.h>
#include <math.h>

#define NN   192
#define DIN_ 67
#define DM_  512
#define NHD  8
#define DFF_ 2048
#define GHC  32
#define NCLS 1000
#define BFULL 256
#define SPLITK 6

typedef __attribute__((ext_vector_type(8))) short s16x8;
typedef __attribute__((ext_vector_type(4))) float f32x4;

__device__ __forceinline__ f32x4 mfma16(s16x8 a, s16x8 b, f32x4 c) {
  return __builtin_amdgcn_mfma_f32_16x16x32_bf16(a, b, c, 0, 0, 0);
}

__device__ __forceinline__ void gload16(const short* g, short* l) {
  __builtin_amdgcn_global_load_lds(
      (const __attribute__((address_space(1))) unsigned int*)g,
      (__attribute__((address_space(3))) unsigned int*)l, 16, 0, 0);
}

__device__ __forceinline__ void split1(float f, short& h, short& l) {
  unsigned u = __float_as_uint(f);
  unsigned hr = (u + 0x7fffu + ((u >> 16) & 1u)) >> 16;
  h = (short)hr;
  float hf = __uint_as_float(hr << 16);
  float d = f - hf;
  unsigned ud = __float_as_uint(d);
  l = (short)((ud + 0x7fffu + ((ud >> 16) & 1u)) >> 16);
}

__device__ __forceinline__ void split4(float4 v, short4& h, short4& l) {
  split1(v.x, h.x, l.x); split1(v.y, h.y, l.y);
  split1(v.z, h.z, l.z); split1(v.w, h.w, l.w);
}

// ------------------------------------------------------------------
__global__ void pe_kernel(float* __restrict__ pe) {
  int n = blockIdx.x;
  int i = threadIdx.x;
  double div = exp((double)(2 * i) * (-log(10000.0) / (double)DM_));
  double a = (double)n * div;
  pe[n * DM_ + 2 * i]     = (float)sin(a);
  pe[n * DM_ + 2 * i + 1] = (float)cos(a);
}

// weight cvt with row padding (rows >= rows are zero)
__global__ __launch_bounds__(256) void cvt_w(
    const float* __restrict__ w, short* __restrict__ hi,
    short* __restrict__ lo, int rows, int K)
{
  int r = blockIdx.y;
  int c4 = blockIdx.x * 256 + threadIdx.x;
  if (c4 * 4 >= K) return;
  float4 v = make_float4(0.f, 0.f, 0.f, 0.f);
  if (r < rows) v = reinterpret_cast<const float4*>(w + (size_t)r * K)[c4];
  short4 h, L; split4(v, h, L);
  reinterpret_cast<short4*>(hi + (size_t)r * K)[c4] = h;
  reinterpret_cast<short4*>(lo + (size_t)r * K)[c4] = L;
}

__global__ void pack_bias(const float* a, const float* b, const float* c, float* o) {
  int i = blockIdx.x * 256 + threadIdx.x;
  if (i < 512) o[i] = a[i];
  else if (i < 1024) o[i] = b[i - 512];
  else if (i < 1536) o[i] = c[i - 1024];
}

// ------------------------------------------------------------------
// Split-bf16 MFMA GEMM: out = act(A @ W^T + bias [+res] [+pe])
// FLAGS: 1 relu, 2 +res, 4 +pe, 8 write bf16 hi/lo of out, 16 skip fp32 C
// ------------------------------------------------------------------
template <int FLAGS>
__global__ __launch_bounds__(256, 2) void gemm_mfma(
    const short* __restrict__ Ahi, const short* __restrict__ Alo,
    const short* __restrict__ Whi, const short* __restrict__ Wlo,
    const float* __restrict__ bias, const float* __restrict__ res,
    const float* __restrict__ pe, float* __restrict__ C,
    short* __restrict__ Ohi, short* __restrict__ Olo,
    int K, int Nout)
{
  __shared__ __align__(16) short lds[4 * 8192];
  const int tid = threadIdx.x;
  const int l = tid & 63, w = tid >> 6;
  const int m0 = blockIdx.x * 128, n0 = blockIdx.y * 128;
  const int wm = w >> 1, wn = w & 1;
  const int lane_r = l & 15, lane_hi = l >> 4, lx = l & 7;

  const int srow = w * 32 + (l >> 3);
  const int slog = (l & 7) ^ (l >> 3);
  size_t aoff[4], woff[4];
  int loff[4];
#pragma unroll
  for (int j = 0; j < 4; j++) {
    aoff[j] = (size_t)(m0 + srow + j * 8) * K + slog * 8;
    woff[j] = (size_t)(n0 + srow + j * 8) * K + slog * 8;
    loff[j] = (w * 32 + j * 8) * 64;
  }

  f32x4 acc[4][4];
#pragma unroll
  for (int a = 0; a < 4; a++)
#pragma unroll
    for (int b = 0; b < 4; b++) acc[a][b] = (f32x4){0.f, 0.f, 0.f, 0.f};

  for (int k0 = 0; k0 < K; k0 += 64) {
#pragma unroll
    for (int j = 0; j < 4; j++) {
      gload16(Ahi + aoff[j] + k0, &lds[0 * 8192 + loff[j]]);
      gload16(Alo + aoff[j] + k0, &lds[1 * 8192 + loff[j]]);
      gload16(Whi + woff[j] + k0, &lds[2 * 8192 + loff[j]]);
      gload16(Wlo + woff[j] + k0, &lds[3 * 8192 + loff[j]]);
    }
    __syncthreads();
#pragma unroll
    for (int ks = 0; ks < 2; ks++) {
      const int ps = (((ks << 2) | lane_hi) ^ lx) << 3;
      s16x8 ah[4], al[4], bh[4], bl[4];
#pragma unroll
      for (int mf = 0; mf < 4; mf++) {
        int off = (wm * 64 + mf * 16 + lane_r) * 64 + ps;
        ah[mf] = *reinterpret_cast<const s16x8*>(&lds[0 * 8192 + off]);
        al[mf] = *reinterpret_cast<const s16x8*>(&lds[1 * 8192 + off]);
      }
#pragma unroll
      for (int nf = 0; nf < 4; nf++) {
        int off = (wn * 64 + nf * 16 + lane_r) * 64 + ps;
        bh[nf] = *reinterpret_cast<const s16x8*>(&lds[2 * 8192 + off]);
        bl[nf] = *reinterpret_cast<const s16x8*>(&lds[3 * 8192 + off]);
      }
#pragma unroll
      for (int mf = 0; mf < 4; mf++)
#pragma unroll
        for (int nf = 0; nf < 4; nf++) {
          acc[mf][nf] = mfma16(ah[mf], bh[nf], acc[mf][nf]);
          acc[mf][nf] = mfma16(ah[mf], bl[nf], acc[mf][nf]);
          acc[mf][nf] = mfma16(al[mf], bh[nf], acc[mf][nf]);
        }
    }
    __syncthreads();
  }

#pragma unroll
  for (int mf = 0; mf < 4; mf++)
#pragma unroll
    for (int nf = 0; nf < 4; nf++) {
      int n = n0 + wn * 64 + nf * 16 + lane_r;
      if (n >= Nout) continue;
      int mb = m0 + wm * 64 + mf * 16 + lane_hi * 4;
      float bn = bias ? bias[n] : 0.f;
#pragma unroll
      for (int j = 0; j < 4; j++) {
        int m = mb + j;
        float v = acc[mf][nf][j] + bn;
        if (FLAGS & 2) v += res[(size_t)m * Nout + n];
        if (FLAGS & 4) v += pe[(m % NN) * DM_ + n];
        if (FLAGS & 1) v = fmaxf(v, 0.f);
        if (!(FLAGS & 16)) C[(size_t)m * Nout + n] = v;
        if (FLAGS & 8) {
          short h, L; split1(v, h, L);
          Ohi[(size_t)m * Nout + n] = h;
          Olo[(size_t)m * Nout + n] = L;
        }
      }
    }
}

// ------------------------------------------------------------------
// fp32 64x64 GEMM; optional hi/lo epilogue write (runtime null check)
// FLAGS: 1 relu, 2 +res
// ------------------------------------------------------------------
#define BM 64
#define BN 64
#define BK 16
#define LDT 68

template <int FLAGS>
__global__ __launch_bounds__(256) void gemm_nt(
    const float* __restrict__ A, const float* __restrict__ W,
    const float* __restrict__ bias, const float* __restrict__ res,
    float* __restrict__ C, short* __restrict__ Ohi, short* __restrict__ Olo,
    int M, int K, int N)
{
  __shared__ __align__(16) float As[BK][LDT];
  __shared__ __align__(16) float Ws[BK][LDT];
  const int tid  = threadIdx.x;
  const int m0   = blockIdx.x * BM;
  const int n0   = blockIdx.y * BN;
  const int ty   = tid >> 4;
  const int tx   = tid & 15;
  const int lrow = tid >> 2;
  const int lk   = (tid & 3) * 4;

  float acc[4][4];
#pragma unroll
  for (int i = 0; i < 4; i++)
#pragma unroll
    for (int j = 0; j < 4; j++) acc[i][j] = 0.f;

  const int mA = m0 + lrow;
  const int nW = n0 + lrow;
  const float* Arow = A + (size_t)mA * K;
  const float* Wrow = W + (size_t)nW * K;
  const bool va = (mA < M);
  const bool vw = (nW < N);

  for (int k0 = 0; k0 < K; k0 += BK) {
#pragma unroll
    for (int j = 0; j < 4; j++) {
      int kk = k0 + lk + j;
      As[lk + j][lrow] = (va && kk < K) ? Arow[kk] : 0.f;
      Ws[lk + j][lrow] = (vw && kk < K) ? Wrow[kk] : 0.f;
    }
    __syncthreads();
#pragma unroll
    for (int kk = 0; kk < BK; kk++) {
      float4 a4 = *reinterpret_cast<const float4*>(&As[kk][ty * 4]);
      float4 b4 = *reinterpret_cast<const float4*>(&Ws[kk][tx * 4]);
      float av[4] = {a4.x, a4.y, a4.z, a4.w};
      float bv[4] = {b4.x, b4.y, b4.z, b4.w};
#pragma unroll
      for (int i = 0; i < 4; i++)
#pragma unroll
        for (int j = 0; j < 4; j++) acc[i][j] += av[i] * bv[j];
    }
    __syncthreads();
  }

#pragma unroll
  for (int i = 0; i < 4; i++) {
    int m = m0 + ty * 4 + i;
#pragma unroll
    for (int j = 0; j < 4; j++) {
      int n = n0 + tx * 4 + j;
      if (m < M && n < N) {
        float v = acc[i][j];
        if (bias) v += bias[n];
        if (FLAGS & 2) v += res[(size_t)m * N + n];
        if (FLAGS & 1) v = fmaxf(v, 0.f);
        C[(size_t)m * N + n] = v;
        if (Ohi) {
          short h, L; split1(v, h, L);
          Ohi[(size_t)m * N + n] = h;
          Olo[(size_t)m * N + n] = L;
        }
      }
    }
  }
}

// ------------------------------------------------------------------
// Deterministic split-K classifier GEMM + reduce
// ------------------------------------------------------------------
__global__ __launch_bounds__(256) void gemm_splitk(
    const float* __restrict__ A, const float* __restrict__ W,
    float* __restrict__ P, int M, int K, int N, int Kc)
{
  __shared__ __align__(16) float As[BK][LDT];
  __shared__ __align__(16) float Ws[BK][LDT];
  const int tid  = threadIdx.x;
  const int m0   = blockIdx.x * BM;
  const int n0   = blockIdx.y * BN;
  const int kb   = blockIdx.z * Kc;
  const int ke   = min(K, kb + Kc);
  const int ty   = tid >> 4;
  const int tx   = tid & 15;
  const int lrow = tid >> 2;
  const int lk   = (tid & 3) * 4;

  float acc[4][4];
#pragma unroll
  for (int i = 0; i < 4; i++)
#pragma unroll
    for (int j = 0; j < 4; j++) acc[i][j] = 0.f;

  const int mA = m0 + lrow;
  const int nW = n0 + lrow;
  const float* Arow = A + (size_t)mA * K;
  const float* Wrow = W + (size_t)nW * K;
  const bool va = (mA < M);
  const bool vw = (nW < N);

  for (int k0 = kb; k0 < ke; k0 += BK) {
#pragma unroll
    for (int j = 0; j < 4; j++) {
      int kk = k0 + lk + j;
      As[lk + j][lrow] = (va && kk < ke) ? Arow[kk] : 0.f;
      Ws[lk + j][lrow] = (vw && kk < ke) ? Wrow[kk] : 0.f;
    }
    __syncthreads();
#pragma unroll
    for (int kk = 0; kk < BK; kk++) {
      float4 a4 = *reinterpret_cast<const float4*>(&As[kk][ty * 4]);
      float4 b4 = *reinterpret_cast<const float4*>(&Ws[kk][tx * 4]);
      float av[4] = {a4.x, a4.y, a4.z, a4.w};
      float bv[4] = {b4.x, b4.y, b4.z, b4.w};
#pragma unroll
      for (int i = 0; i < 4; i++)
#pragma unroll
        for (int j = 0; j < 4; j++) acc[i][j] += av[i] * bv[j];
    }
    __syncthreads();
  }

  float* Pz = P + (size_t)blockIdx.z * M * N;
#pragma unroll
  for (int i = 0; i < 4; i++) {
    int m = m0 + ty * 4 + i;
#pragma unroll
    for (int j = 0; j < 4; j++) {
      int n = n0 + tx * 4 + j;
      if (m < M && n < N) Pz[(size_t)m * N + n] = acc[i][j];
    }
  }
}

__global__ __launch_bounds__(256) void splitk_reduce(
    const float* __restrict__ P, const float* __restrict__ bias,
    float* __restrict__ y, int M, int N)
{
  int i = blockIdx.x * 256 + threadIdx.x;
  if (i >= M * N) return;
  int n = i % N;
  float s = bias[n];
#pragma unroll
  for (int z = 0; z < SPLITK; z++) s += P[(size_t)z * M * N + i];
  y[i] = s;
}

// ------------------------------------------------------------------
// Flash attention per (b,h); QKV fused layout [M1,1536] (q|k|v).
// Keys unrolled x2, 4-way split dot accumulators, __expf.
// Output written as bf16 hi/lo only (layout [M1][512]).
// ------------------------------------------------------------------
__global__ __launch_bounds__(192) void attn_kernel(
    const float* __restrict__ QKV, short* __restrict__ Ohi,
    short* __restrict__ Olo)
{
  __shared__ __align__(16) float Ks[64][64];
  __shared__ __align__(16) float Vs[64][64];
  const int b = blockIdx.x >> 3;
  const int h = blockIdx.x & 7;
  const int r = threadIdx.x;
  const float* Qb = QKV + (size_t)(b * NN) * 1536 + h * 64;

  float q[64], o[64];
  {
    const float4* qp = reinterpret_cast<const float4*>(Qb + (size_t)r * 1536);
#pragma unroll
    for (int d4 = 0; d4 < 16; d4++) {
      float4 t = qp[d4];
      q[4 * d4 + 0] = t.x; q[4 * d4 + 1] = t.y;
      q[4 * d4 + 2] = t.z; q[4 * d4 + 3] = t.w;
    }
  }
#pragma unroll
  for (int d = 0; d < 64; d++) o[d] = 0.f;
  float m = -3.0e38f, l = 0.f;

  for (int kt = 0; kt < 3; kt++) {
    for (int idx = threadIdx.x; idx < 64 * 16; idx += 192) {
      int row = idx >> 4, c4 = idx & 15;
      const float4* kp = reinterpret_cast<const float4*>(Qb + 512 + (size_t)(kt * 64 + row) * 1536);
      const float4* vp = reinterpret_cast<const float4*>(Qb + 1024 + (size_t)(kt * 64 + row) * 1536);
      reinterpret_cast<float4*>(&Ks[row][0])[c4] = kp[c4];
      reinterpret_cast<float4*>(&Vs[row][0])[c4] = vp[c4];
    }
    __syncthreads();
#pragma unroll 2
    for (int j = 0; j < 64; j += 2) {
      const float4* kr0 = reinterpret_cast<const float4*>(&Ks[j][0]);
      const float4* kr1 = reinterpret_cast<const float4*>(&Ks[j + 1][0]);
      float sa[4] = {0.f, 0.f, 0.f, 0.f};
      float sb[4] = {0.f, 0.f, 0.f, 0.f};
#pragma unroll
      for (int d4 = 0; d4 < 16; d4++) {
        float4 t0 = kr0[d4];
        float4 t1 = kr1[d4];
        int a = d4 & 3;
        sa[a] += q[4 * d4 + 0] * t0.x + q[4 * d4 + 1] * t0.y +
                 q[4 * d4 + 2] * t0.z + q[4 * d4 + 3] * t0.w;
        sb[a] += q[4 * d4 + 0] * t1.x + q[4 * d4 + 1] * t1.y +
                 q[4 * d4 + 2] * t1.z + q[4 * d4 + 3] * t1.w;
      }
      float s0 = ((sa[0] + sa[1]) + (sa[2] + sa[3])) * 0.125f;
      float s1 = ((sb[0] + sb[1]) + (sb[2] + sb[3])) * 0.125f;
      float nm = fmaxf(m, fmaxf(s0, s1));
      float corr = __expf(m - nm);
      float p0 = __expf(s0 - nm);
      float p1 = __expf(s1 - nm);
      m = nm;
      l = l * corr + p0 + p1;
      const float4* vr0 = reinterpret_cast<const float4*>(&Vs[j][0]);
      const float4* vr1 = reinterpret_cast<const float4*>(&Vs[j + 1][0]);
#pragma unroll
      for (int d4 = 0; d4 < 16; d4++) {
        float4 t0 = vr0[d4];
        float4 t1 = vr1[d4];
        o[4 * d4 + 0] = o[4 * d4 + 0] * corr + p0 * t0.x + p1 * t1.x;
        o[4 * d4 + 1] = o[4 * d4 + 1] * corr + p0 * t0.y + p1 * t1.y;
        o[4 * d4 + 2] = o[4 * d4 + 2] * corr + p0 * t0.z + p1 * t1.z;
        o[4 * d4 + 3] = o[4 * d4 + 3] * corr + p0 * t0.w + p1 * t1.w;
      }
    }
    __syncthreads();
  }
  float inv = 1.f / l;
  const size_t ob = (size_t)(b * NN + r) * DM_ + h * 64;
#pragma unroll
  for (int d4 = 0; d4 < 16; d4++) {
    float4 t;
    t.x = o[4 * d4 + 0] * inv; t.y = o[4 * d4 + 1] * inv;
    t.z = o[4 * d4 + 2] * inv; t.w = o[4 * d4 + 3] * inv;
    short4 h4, L4; split4(t, h4, L4);
    reinterpret_cast<short4*>(Ohi + ob)[d4] = h4;
    reinterpret_cast<short4*>(Olo + ob)[d4] = L4;
  }
}

// ------------------------------------------------------------------
__global__ __launch_bounds__(256) void ln_kernel(
    const float* __restrict__ in, float* __restrict__ out,
    const float* __restrict__ g, const float* __restrict__ be,
    short* __restrict__ Ohi, short* __restrict__ Olo)
{
  const size_t row = blockIdx.x;
  const int tid = threadIdx.x;
  float e0 = in[row * DM_ + tid];
  float e1 = in[row * DM_ + 256 + tid];
  __shared__ float red[8];
  float s = e0 + e1;
#pragma unroll
  for (int off = 32; off; off >>= 1) s += __shfl_xor(s, off);
  int wv = tid >> 6, lane = tid & 63;
  if (lane == 0) red[wv] = s;
  __syncthreads();
  float mean = (red[0] + red[1] + red[2] + red[3]) * (1.f / 512.f);
  float d0 = e0 - mean, d1 = e1 - mean;
  float sq = d0 * d0 + d1 * d1;
#pragma unroll
  for (int off = 32; off; off >>= 1) sq += __shfl_xor(sq, off);
  if (lane == 0) red[4 + wv] = sq;
  __syncthreads();
  float var = (red[4] + red[5] + red[6] + red[7]) * (1.f / 512.f);
  float inv = 1.f / sqrtf(var + 1e-5f);
  float v0 = d0 * inv * g[tid] + be[tid];
  float v1 = d1 * inv * g[256 + tid] + be[256 + tid];
  out[row * DM_ + tid]       = v0;
  out[row * DM_ + 256 + tid] = v1;
  short h, L;
  split1(v0, h, L); Ohi[row * DM_ + tid] = h;       Olo[row * DM_ + tid] = L;
  split1(v1, h, L); Ohi[row * DM_ + 256 + tid] = h; Olo[row * DM_ + 256 + tid] = L;
}

// ------------------------------------------------------------------
__global__ __launch_bounds__(1024) void symk(
    const float* __restrict__ madj, const float* __restrict__ adj,
    float* __restrict__ nadj_out, float* __restrict__ as_out,
    float* __restrict__ nadjT)
{
  __shared__ float t1[32][33];
  __shared__ float t2[32][33];
  __shared__ float tn[32][33];
  const int b  = blockIdx.z;
  const int i0 = blockIdx.y * 32, j0 = blockIdx.x * 32;
  const int tx = threadIdx.x, ty = threadIdx.y;
  const size_t bb = (size_t)b * NN * NN;
  t1[ty][tx] = madj[bb + (size_t)(i0 + ty) * NN + j0 + tx];
  t2[ty][tx] = madj[bb + (size_t)(j0 + ty) * NN + i0 + tx];
  __syncthreads();
  float mij = t1[ty][tx], mji = t2[tx][ty];
  float sS = 0.5f * (mij + mji);
  float sA = 0.5f * (mij - mji);
  float na = fmaxf(adj[bb + (size_t)(i0 + ty) * NN + j0 + tx] + sS, 0.f);
  nadj_out[bb + (size_t)(i0 + ty) * NN + j0 + tx] = na;
  as_out[bb + (size_t)(i0 + ty) * NN + j0 + tx]   = sA;
  tn[ty][tx] = na;
  __syncthreads();
  nadjT[bb + (size_t)(j0 + ty) * NN + i0 + tx] = tn[tx][ty];
}

// ------------------------------------------------------------------
__global__ __launch_bounds__(256) void gat_kernel(
    const float* __restrict__ xp, const float* __restrict__ nadjT,
    const float* __restrict__ a_s, const float* __restrict__ a_d,
    const float* __restrict__ bg, float* __restrict__ xg)
{
  __shared__ float xps[NN][33];
  __shared__ float es[2][NN];
  __shared__ float ed[2][NN];
  __shared__ float al[4][2][NN];
  const int b  = blockIdx.x;
  const int qq = blockIdx.y;
  const int tid = threadIdx.x;

  for (int idx = tid; idx < NN * 32; idx += 256) {
    int n = idx >> 5, c = idx & 31;
    xps[n][c] = xp[((size_t)b * NN + n) * 32 + c];
  }
  __syncthreads();
  for (int t = tid; t < 4 * NN; t += 256) {
    int n = t % NN;
    int h = (t / NN) & 1;
    int which = t / (2 * NN);
    const float* av = which ? a_d : a_s;
    float sum = 0.f;
#pragma unroll
    for (int c = 0; c < 16; c++) sum += xps[n][h * 16 + c] * av[h * 16 + c];
    if (which) ed[h][n] = sum; else es[h][n] = sum;
  }
  __syncthreads();

  const int w = tid >> 6, lane = tid & 63;
  for (int dst = qq * 48 + w; dst < qq * 48 + 48; dst += 4) {
    float ed0 = ed[0][dst], ed1 = ed[1][dst];
    float e0[3], e1[3];
    float mx0 = -3e38f, mx1 = -3e38f;
    const float* nrow = nadjT + ((size_t)b * NN + dst) * NN;
#pragma unroll
    for (int s3 = 0; s3 < 3; s3++) {
      int src = lane + 64 * s3;
      bool mk = (nrow[src] > 0.f) || (src == dst);
      float a0 = es[0][src] + ed0; a0 = (a0 > 0.f) ? a0 : 0.2f * a0;
      float a1 = es[1][src] + ed1; a1 = (a1 > 0.f) ? a1 : 0.2f * a1;
      e0[s3] = mk ? a0 : -1e9f;
      e1[s3] = mk ? a1 : -1e9f;
      mx0 = fmaxf(mx0, e0[s3]); mx1 = fmaxf(mx1, e1[s3]);
    }
#pragma unroll
    for (int off = 32; off; off >>= 1) {
      mx0 = fmaxf(mx0, __shfl_xor(mx0, off));
      mx1 = fmaxf(mx1, __shfl_xor(mx1, off));
    }
    float s0 = 0.f, s1 = 0.f, p0[3], p1[3];
#pragma unroll
    for (int s3 = 0; s3 < 3; s3++) {
      p0[s3] = __expf(e0[s3] - mx0); s0 += p0[s3];
      p1[s3] = __expf(e1[s3] - mx1); s1 += p1[s3];
    }
#pragma unroll
    for (int off = 32; off; off >>= 1) {
      s0 += __shfl_xor(s0, off);
      s1 += __shfl_xor(s1, off);
    }
    float i0 = 1.f / s0, i1 = 1.f / s1;
#pragma unroll
    for (int s3 = 0; s3 < 3; s3++) {
      int src = lane + 64 * s3;
      al[w][0][src] = p0[s3] * i0;
      al[w][1][src] = p1[s3] * i1;
    }
    int half = lane >> 5;
    int hh = (lane >> 4) & 1, cc = lane & 15;
    float acc = 0.f;
    for (int src = half * 96; src < half * 96 + 96; src++) {
      acc += al[w][hh][src] * xps[src][hh * 16 + cc];
    }
    acc += __shfl_xor(acc, 32);
    if (lane < 32) {
      float v = acc + bg[lane];
      xg[((size_t)b * NN + dst) * 32 + lane] = fmaxf(v, 0.f);
    }
  }
}

// ------------------------------------------------------------------
extern "C" void kernel_launch(void* const* d_in, const int* in_sizes, int n_in,
                              void* d_out, int out_size, void* d_ws, size_t ws_size,
                              hipStream_t stream)
{
  const float* x    = (const float*)d_in[0];
  const float* adj  = (const float*)d_in[1];
  const float* W_up = (const float*)d_in[3];
  const float* b_up = (const float*)d_in[4];
  const float* W_lin= (const float*)d_in[5];
  const float* b_lin= (const float*)d_in[6];
  const float* Wq = (const float*)d_in[7];   const float* bq = (const float*)d_in[8];
  const float* Wk = (const float*)d_in[9];   const float* bk = (const float*)d_in[10];
  const float* Wv = (const float*)d_in[11];  const float* bv = (const float*)d_in[12];
  const float* Wo = (const float*)d_in[13];  const float* bo = (const float*)d_in[14];
  const float* g1 = (const float*)d_in[15];  const float* be1= (const float*)d_in[16];
  const float* W1 = (const float*)d_in[17];  const float* b1 = (const float*)d_in[18];
  const float* W2 = (const float*)d_in[19];  const float* b2 = (const float*)d_in[20];
  const float* g2 = (const float*)d_in[21];  const float* be2= (const float*)d_in[22];
  const float* W_map=(const float*)d_in[23]; const float* b_map=(const float*)d_in[24];
  const float* Wg1= (const float*)d_in[25];  const float* as1=(const float*)d_in[26];
  const float* ad1= (const float*)d_in[27];  const float* bg1=(const float*)d_in[28];
  const float* Wg2= (const float*)d_in[29];  const float* as2=(const float*)d_in[30];
  const float* ad2= (const float*)d_in[31];  const float* bg2=(const float*)d_in[32];
  const float* Wg3= (const float*)d_in[33];  const float* as3=(const float*)d_in[34];
  const float* ad3= (const float*)d_in[35];  const float* bg3=(const float*)d_in[36];
  const float* Wcls=(const float*)d_in[37];  const float* bcls=(const float*)d_in[38];

  float* ws = (float*)d_ws;
  const size_t avail = ws_size / 4;
  int CB = 256;
  while (CB > 2 && 3474944ULL + (size_t)CB * 1075056ULL > avail) CB >>= 1;

  size_t off = 0;
  float* pe   = ws;                      off += 98304;
  short* wsh  = (short*)(ws + off);      off += 3375104;   // hi/lo weights
  float* qkvb = ws + off;                off += 1536;
  float* buf0 = ws + off;                off += (size_t)CB * 36864;   // h0 / madj
  float* bh   = ws + off;                off += (size_t)CB * 98304;   // residual h
  float* bqkv = ws + off;                off += (size_t)CB * 294912;  // fused qkv
  float* bsc  = ws + off;                off += (size_t)CB * 98304;   // pre-LN scratch
  float* bnT  = ws + off;                off += (size_t)CB * 36864;   // nadj^T
  float* bgp  = ws + off;                off += (size_t)CB * 6144;
  float* bgg  = ws + off;                off += (size_t)CB * 6144;
  short* pA_hi = (short*)(ws + off);     off += (size_t)CB * 196608;  // M1 x 2048
  short* pA_lo = (short*)(ws + off);     off += (size_t)CB * 196608;
  short* pB_hi = (short*)(ws + off);     off += (size_t)CB * 49152;   // M1 x 512
  short* pB_lo = (short*)(ws + off);     off += (size_t)CB * 49152;
  float* bpart = ws + off;               off += (size_t)CB * SPLITK * 1000;

  short* Wlin_hi = wsh;                     short* Wlin_lo = Wlin_hi + 98304;
  short* Wqkv_hi = Wlin_lo + 98304;         short* Wqkv_lo = Wqkv_hi + 786432;
  short* Wo_hi   = Wqkv_lo + 786432;        short* Wo_lo   = Wo_hi + 262144;
  short* W1_hi   = Wo_lo + 262144;          short* W1_lo   = W1_hi + 1048576;
  short* W2_hi   = W1_lo + 1048576;         short* W2_lo   = W2_hi + 1048576;
  short* Wm_hi   = W2_lo + 1048576;         short* Wm_lo   = Wm_hi + 131072;

  float* y_out    = (float*)d_out;
  float* nadj_out = y_out + (size_t)BFULL * NCLS;
  float* as_out   = nadj_out + (size_t)BFULL * NN * NN;

  pe_kernel<<<dim3(NN), dim3(256), 0, stream>>>(pe);
  pack_bias<<<dim3(6), dim3(256), 0, stream>>>(bq, bk, bv, qkvb);
  auto CW = [&](const float* w, short* hi, short* lo, int rows, int rpad, int K) {
    cvt_w<<<dim3((K / 4 + 255) / 256, rpad), dim3(256), 0, stream>>>(w, hi, lo, rows, K);
  };
  CW(W_lin, Wlin_hi, Wlin_lo, 512, 512, 192);
  CW(Wq, Wqkv_hi,          Wqkv_lo,          512, 512, 512);
  CW(Wk, Wqkv_hi + 262144, Wqkv_lo + 262144, 512, 512, 512);
  CW(Wv, Wqkv_hi + 524288, Wqkv_lo + 524288, 512, 512, 512);
  CW(Wo, Wo_hi, Wo_lo, 512, 512, 512);
  CW(W1, W1_hi, W1_lo, 2048, 2048, 512);
  CW(W2, W2_hi, W2_lo, 512, 512, 2048);
  CW(W_map, Wm_hi, Wm_lo, 192, 256, 512);

  for (int b0 = 0; b0 < BFULL; b0 += CB) {
    const int M1 = CB * NN;
    const float* x_c   = x   + (size_t)b0 * NN * DIN_;
    const float* adj_c = adj + (size_t)b0 * NN * NN;
    dim3 blk(256);

    // h0 = x@W_up^T + b_up + adj  -> fp32 buf0 + hi/lo into pA (stride 192)
    gemm_nt<2><<<dim3(M1 / 64, 3), blk, 0, stream>>>(
        x_c, W_up, b_up, adj_c, buf0, pA_hi, pA_lo, M1, DIN_, NN);
    // h = h0@W_lin^T + b_lin + pe -> fp32 bh + hi/lo pB
    gemm_mfma<4 | 8><<<dim3(M1 / 128, 4), blk, 0, stream>>>(
        pA_hi, pA_lo, Wlin_hi, Wlin_lo, b_lin, nullptr, pe, bh, pB_hi, pB_lo, NN, DM_);
    // qkv = h@Wqkv^T + b -> fp32 bqkv
    gemm_mfma<0><<<dim3(M1 / 128, 12), blk, 0, stream>>>(
        pB_hi, pB_lo, Wqkv_hi, Wqkv_lo, qkvb, nullptr, nullptr, bqkv, nullptr, nullptr, DM_, 1536);
    // attention -> hi/lo pA (stride 512)
    attn_kernel<<<dim3(CB * NHD), dim3(NN), 0, stream>>>(bqkv, pA_hi, pA_lo);
    // o-proj + residual -> fp32 bsc
    gemm_mfma<2><<<dim3(M1 / 128, 4), blk, 0, stream>>>(
        pA_hi, pA_lo, Wo_hi, Wo_lo, bo, bh, nullptr, bsc, nullptr, nullptr, DM_, DM_);
    // ln1 -> fp32 bh + hi/lo pB
    ln_kernel<<<dim3(M1), blk, 0, stream>>>(bsc, bh, g1, be1, pB_hi, pB_lo);
    // ffn1 (relu) -> hi/lo pA only (stride 2048)
    gemm_mfma<1 | 8 | 16><<<dim3(M1 / 128, 16), blk, 0, stream>>>(
        pB_hi, pB_lo, W1_hi, W1_lo, b1, nullptr, nullptr, nullptr, pA_hi, pA_lo, DM_, DFF_);
    // ffn2 + residual -> fp32 bsc
    gemm_mfma<2><<<dim3(M1 / 128, 4), blk, 0, stream>>>(
        pA_hi, pA_lo, W2_hi, W2_lo, b2, bh, nullptr, bsc, nullptr, nullptr, DFF_, DM_);
    // ln2 -> fp32 bh (unused) + hi/lo pB
    ln_kernel<<<dim3(M1), blk, 0, stream>>>(bsc, bh, g2, be2, pB_hi, pB_lo);
    // madj -> fp32 buf0 (Npad 256, Nout 192)
    gemm_mfma<0><<<dim3(M1 / 128, 2), blk, 0, stream>>>(
        pB_hi, pB_lo, Wm_hi, Wm_lo, b_map, nullptr, nullptr, buf0, nullptr, nullptr, DM_, NN);
    symk<<<dim3(6, 6, CB), dim3(32, 32), 0, stream>>>(
        buf0, adj_c,
        nadj_out + (size_t)b0 * NN * NN,
        as_out   + (size_t)b0 * NN * NN,
        bnT);

    // GAT stack
    gemm_nt<0><<<dim3(M1 / 64, 1), blk, 0, stream>>>(
        x_c, Wg1, nullptr, nullptr, bgp, nullptr, nullptr, M1, DIN_, GHC);
    gat_kernel<<<dim3(CB, 4), blk, 0, stream>>>(bgp, bnT, as1, ad1, bg1, bgg);
    gemm_nt<0><<<dim3(M1 / 64, 1), blk, 0, stream>>>(
        bgg, Wg2, nullptr, nullptr, bgp, nullptr, nullptr, M1, GHC, GHC);
    gat_kernel<<<dim3(CB, 4), blk, 0, stream>>>(bgp, bnT, as2, ad2, bg2, bgg);
    gemm_nt<0><<<dim3(M1 / 64, 1), blk, 0, stream>>>(
        bgg, Wg3, nullptr, nullptr, bgp, nullptr, nullptr, M1, GHC, GHC);
    gat_kernel<<<dim3(CB, 4), blk, 0, stream>>>(bgp, bnT, as3, ad3, bg3, bgg);

    // classifier
    gemm_splitk<<<dim3((CB + 63) / 64, (NCLS + 63) / 64, SPLITK), blk, 0, stream>>>(
        bgg, Wcls, bpart, CB, NN * GHC, NCLS, 1024);
    splitk_reduce<<<dim3((CB * NCLS + 255) / 256), blk, 0, stream>>>(
        bpart, bcls, y_out + (size_t)b0 * NCLS, CB, NCLS);
  }
}